// Round 1
// baseline (356.124 us; speedup 1.0000x reference)
//
#include <hip/hip_runtime.h>
#include <cstdint>
#include <cstddef>

#define GRID_N 4096
#define DIM    256
#define BATCH  4096

// ws float offsets
#define OFF_S     0u
#define OFF_CNT   1048576u
#define OFF_GX    1052672u
#define OFF_WCNT  1056768u
#define OFF_SCR   1060864u            // scratch union start
#define OFF_XN    (OFF_SCR)           // 4096
#define OFF_CN    (OFF_SCR + 4096u)   // 4096
#define OFF_MD    (OFF_SCR + 8192u)   // 4096
#define OFF_PV    (OFF_SCR + 12288u)  // 131072
#define OFF_PI    (OFF_SCR + 143360u) // 131072
#define OFF_U     (OFF_SCR)           // 1048576 (overlaps scratch; dead by then)

// out float offsets
#define OUT_BMU   1048576u
#define OUT_MD    1056768u

// ---------------- norms: |x_b|^2 and |c_g|^2 ----------------
__global__ __launch_bounds__(256) void norm_kernel(const float* __restrict__ x,
                                                   const float* __restrict__ cen,
                                                   float* __restrict__ xn,
                                                   float* __restrict__ cn) {
  int row  = blockIdx.x * 4 + (threadIdx.x >> 6);
  int lane = threadIdx.x & 63;
  const float* src = (row < BATCH) ? (x + (size_t)row * DIM)
                                   : (cen + (size_t)(row - BATCH) * DIM);
  float4 v = *(const float4*)(src + lane * 4);
  float s = v.x * v.x + v.y * v.y + v.z * v.z + v.w * v.w;
#pragma unroll
  for (int off = 32; off >= 1; off >>= 1) s += __shfl_xor(s, off);
  if (lane == 0) {
    if (row < BATCH) xn[row] = s;
    else             cn[row - BATCH] = s;
  }
}

// ---------------- Gaussian factor Gx[a][b] = exp(-(a-b)^2/den) ----------------
__global__ __launch_bounds__(256) void gx_kernel(const float* __restrict__ lr,
                                                 float* __restrict__ Gx) {
  int g = blockIdx.x * 256 + threadIdx.x;
  float sg = 32.f * lr[0];
  float inv = 1.f / (2.f * sg * sg + 1e-5f);
  int a = g >> 6, b = g & 63;
  float d = (float)(a - b);
  Gx[g] = expf(-d * d * inv);
}

// ---------------- fused fp32 GEMM (x @ cen^T) + per-row argmin of cnorm-2*dot ---
__global__ __launch_bounds__(256) void gemm_argmin_kernel(
    const float* __restrict__ x, const float* __restrict__ cen,
    const float* __restrict__ cnorm, float* __restrict__ pv, int* __restrict__ pi) {
  __shared__ float sm[8448];          // As[32][132] + Bs[32][132]
  float* As = sm;
  float* Bs = sm + 4224;
  const int tid = threadIdx.x;
  const int tx = tid & 15, ty = tid >> 4;
  const int row0 = blockIdx.y * 128, col0 = blockIdx.x * 128;

  float acc[8][8];
#pragma unroll
  for (int i = 0; i < 8; i++)
#pragma unroll
    for (int j = 0; j < 8; j++) acc[i][j] = 0.f;

  for (int kt = 0; kt < DIM; kt += 32) {
#pragma unroll
    for (int p = 0; p < 4; p++) {
      int idx = p * 256 + tid;
      int r = idx >> 3, kq = (idx & 7) * 4;
      float4 va = *(const float4*)(x   + (size_t)(row0 + r) * DIM + kt + kq);
      float4 vb = *(const float4*)(cen + (size_t)(col0 + r) * DIM + kt + kq);
      As[(kq + 0) * 132 + r] = va.x;
      As[(kq + 1) * 132 + r] = va.y;
      As[(kq + 2) * 132 + r] = va.z;
      As[(kq + 3) * 132 + r] = va.w;
      Bs[(kq + 0) * 132 + r] = vb.x;
      Bs[(kq + 1) * 132 + r] = vb.y;
      Bs[(kq + 2) * 132 + r] = vb.z;
      Bs[(kq + 3) * 132 + r] = vb.w;
    }
    __syncthreads();
#pragma unroll
    for (int k = 0; k < 32; k++) {
      float4 a0 = *(const float4*)&As[k * 132 + ty * 8];
      float4 a1 = *(const float4*)&As[k * 132 + ty * 8 + 4];
      float4 b0 = *(const float4*)&Bs[k * 132 + tx * 4];
      float4 b1 = *(const float4*)&Bs[k * 132 + 64 + tx * 4];
      float a[8] = {a0.x, a0.y, a0.z, a0.w, a1.x, a1.y, a1.z, a1.w};
      float b[8] = {b0.x, b0.y, b0.z, b0.w, b1.x, b1.y, b1.z, b1.w};
#pragma unroll
      for (int i = 0; i < 8; i++)
#pragma unroll
        for (int j = 0; j < 8; j++) acc[i][j] += a[i] * b[j];
    }
    __syncthreads();
  }

  // epilogue: v = cnorm[c] - 2*dot ; per-row argmin (first-min tie-break)
  float cnv[8];
#pragma unroll
  for (int j = 0; j < 4; j++) cnv[j] = cnorm[col0 + tx * 4 + j];
#pragma unroll
  for (int j = 0; j < 4; j++) cnv[4 + j] = cnorm[col0 + 64 + tx * 4 + j];

  float* rv = sm;                  // [128][16] reuse LDS
  int*   ri = (int*)(sm + 2048);   // [128][16]
#pragma unroll
  for (int i = 0; i < 8; i++) {
    float bv = 1e30f; int bi = 0x7fffffff;
#pragma unroll
    for (int j = 0; j < 8; j++) {
      int c = col0 + ((j < 4) ? (tx * 4 + j) : (64 + tx * 4 + (j - 4)));
      float v = cnv[j] - 2.f * acc[i][j];
      if (v < bv) { bv = v; bi = c; }   // ascending cols within thread
    }
    rv[(ty * 8 + i) * 16 + tx] = bv;
    ri[(ty * 8 + i) * 16 + tx] = bi;
  }
  __syncthreads();
  if (tid < 128) {
    float bv = 1e30f; int bi = 0x7fffffff;
    for (int t = 0; t < 16; t++) {
      float v = rv[tid * 16 + t]; int c = ri[tid * 16 + t];
      if (v < bv || (v == bv && c < bi)) { bv = v; bi = c; }  // index tie-break
    }
    pv[(size_t)(row0 + tid) * 32 + blockIdx.x] = bv;
    pi[(size_t)(row0 + tid) * 32 + blockIdx.x] = bi;
  }
}

// ---------------- finalize: BMU per row, bmu_loc out, scatter S/cnt ----------------
__global__ __launch_bounds__(256) void finalize_kernel(
    const float* __restrict__ pv, const int* __restrict__ pi,
    const float* __restrict__ xn, const float* __restrict__ x,
    float* __restrict__ S, float* __restrict__ cnt,
    float* __restrict__ md, float* __restrict__ out) {
  const int b = blockIdx.x;
  const int tid = threadIdx.x;
  __shared__ int sbmu;
  if (tid < 64) {
    float v = 1e30f; int idx = 0x7fffffff;
    if (tid < 32) { v = pv[(size_t)b * 32 + tid]; idx = pi[(size_t)b * 32 + tid]; }
#pragma unroll
    for (int off = 16; off >= 1; off >>= 1) {
      float ov = __shfl_xor(v, off);
      int oi = __shfl_xor(idx, off);
      if (ov < v || (ov == v && oi < idx)) { v = ov; idx = oi; }
    }
    if (tid == 0) {
      sbmu = idx;
      float d2 = xn[b] + v;
      md[b] = sqrtf(fmaxf(d2, 0.f));
      // locations = meshgrid(ij) -> (g/64, g%64); avoids reading int64/int32 input
      out[OUT_BMU + (size_t)b * 2 + 0] = (float)(idx >> 6);
      out[OUT_BMU + (size_t)b * 2 + 1] = (float)(idx & 63);
      atomicAdd(cnt + idx, 1.f);
    }
  }
  __syncthreads();
  int bmu = sbmu;
  atomicAdd(S + (size_t)bmu * DIM + tid, x[(size_t)b * DIM + tid]);
}

// ---------------- mean(mindist) ----------------
__global__ __launch_bounds__(256) void mdreduce_kernel(const float* __restrict__ md,
                                                       float* __restrict__ out) {
  int t = threadIdx.x;
  float s = 0.f;
#pragma unroll
  for (int i = 0; i < 16; i++) s += md[i * 256 + t];
#pragma unroll
  for (int off = 32; off >= 1; off >>= 1) s += __shfl_xor(s, off);
  __shared__ float w[4];
  if ((t & 63) == 0) w[t >> 6] = s;
  __syncthreads();
  if (t == 0) out[OUT_MD] = (w[0] + w[1] + w[2] + w[3]) * (1.f / (float)BATCH);
}

// ---------------- Wcnt = (Gx (x) Gx) @ cnt  (uses Gx symmetry for bank-free reads) --
__global__ __launch_bounds__(256) void wcnt_kernel(const float* __restrict__ cnt,
                                                   const float* __restrict__ Gx,
                                                   float* __restrict__ Wcnt) {
  __shared__ float cs[4096], gs[4096], inner[4096];
  const int t = threadIdx.x;
  for (int i = 0; i < 16; i++) { cs[i * 256 + t] = cnt[i * 256 + t]; gs[i * 256 + t] = Gx[i * 256 + t]; }
  __syncthreads();
  // inner[ki*64+gj] = sum_kj Gx[gj][kj]*cnt[ki][kj]  (Gx symmetric: Gx[gj][kj]=Gx[kj][gj])
  for (int i = 0; i < 16; i++) {
    int idx = i * 256 + t; int ki = idx >> 6, gj = idx & 63;
    float a = 0.f;
    for (int kj = 0; kj < 64; kj++) a += gs[kj * 64 + gj] * cs[ki * 64 + kj];
    inner[idx] = a;
  }
  __syncthreads();
  const int g = blockIdx.x * 256 + t, gi = g >> 6, gj = g & 63;
  float a = 0.f;
  for (int ki = 0; ki < 64; ki++) a += gs[gi * 64 + ki] * inner[ki * 64 + gj];
  Wcnt[g] = a;
}

// ---------------- U[gi][kj][d] = sum_ki Gx[gi][ki] * S[ki][kj][d] ----------------
__global__ __launch_bounds__(256) void e1_kernel(const float* __restrict__ S,
                                                 const float* __restrict__ Gx,
                                                 float* __restrict__ U) {
  __shared__ float Ss[64 * 256];   // 64 KiB
  const int t = threadIdx.x;
  const int kj = blockIdx.x;
  for (int ki = 0; ki < 64; ki++)
    Ss[ki * 256 + t] = S[((size_t)ki * 64 + kj) * 256 + t];
  __syncthreads();
  for (int g0 = 0; g0 < 64; g0 += 8) {
    float a[8] = {0, 0, 0, 0, 0, 0, 0, 0};
    for (int ki = 0; ki < 64; ki++) {
      float s = Ss[ki * 256 + t];
#pragma unroll
      for (int q = 0; q < 8; q++) a[q] += Gx[(g0 + q) * 64 + ki] * s;  // uniform->s_load
    }
#pragma unroll
    for (int q = 0; q < 8; q++)
      U[((size_t)(g0 + q) * 64 + kj) * 256 + t] = a[q];
  }
}

// -------- V[gi][gj][d] = sum_kj Gx[gj][kj]*U[gi][kj][d]; fused final centroid write --
__global__ __launch_bounds__(256) void e2_kernel(const float* __restrict__ U,
                                                 const float* __restrict__ Gx,
                                                 const float* __restrict__ Wcnt,
                                                 const float* __restrict__ cen,
                                                 const float* __restrict__ lr,
                                                 float* __restrict__ out) {
  __shared__ float Us[64 * 256];   // 64 KiB
  const int t = threadIdx.x;
  const int gi = blockIdx.x;
  for (int kj = 0; kj < 64; kj++)
    Us[kj * 256 + t] = U[((size_t)gi * 64 + kj) * 256 + t];
  __syncthreads();
  const float coef = 0.5f * lr[0] / (float)BATCH;   // alpha_op / B
  for (int g0 = 0; g0 < 64; g0 += 8) {
    float a[8] = {0, 0, 0, 0, 0, 0, 0, 0};
    for (int kj = 0; kj < 64; kj++) {
      float s = Us[kj * 256 + t];
#pragma unroll
      for (int q = 0; q < 8; q++) a[q] += Gx[(g0 + q) * 64 + kj] * s;
    }
#pragma unroll
    for (int q = 0; q < 8; q++) {
      int g = gi * 64 + g0 + q;
      float c = cen[(size_t)g * 256 + t];
      out[(size_t)g * 256 + t] = c + coef * (a[q] - Wcnt[g] * c);
    }
  }
}

extern "C" void kernel_launch(void* const* d_in, const int* in_sizes, int n_in,
                              void* d_out, int out_size, void* d_ws, size_t ws_size,
                              hipStream_t stream) {
  const float* x   = (const float*)d_in[0];
  const float* cen = (const float*)d_in[1];
  const float* lr  = (const float*)d_in[4];
  float* out = (float*)d_out;
  float* ws  = (float*)d_ws;

  float* S    = ws + OFF_S;
  float* cnt  = ws + OFF_CNT;
  float* Gx   = ws + OFF_GX;
  float* Wcnt = ws + OFF_WCNT;
  float* xn   = ws + OFF_XN;
  float* cnw  = ws + OFF_CN;
  float* md   = ws + OFF_MD;
  float* pv   = ws + OFF_PV;
  int*   pi   = (int*)(ws + OFF_PI);
  float* U    = ws + OFF_U;

  hipMemsetAsync(S, 0, (size_t)(1048576 + 4096) * sizeof(float), stream);  // S + cnt
  norm_kernel<<<2048, 256, 0, stream>>>(x, cen, xn, cnw);
  gx_kernel<<<16, 256, 0, stream>>>(lr, Gx);
  gemm_argmin_kernel<<<dim3(32, 32), 256, 0, stream>>>(x, cen, cnw, pv, pi);
  finalize_kernel<<<4096, 256, 0, stream>>>(pv, pi, xn, x, S, cnt, md, out);
  mdreduce_kernel<<<1, 256, 0, stream>>>(md, out);
  wcnt_kernel<<<16, 256, 0, stream>>>(cnt, Gx, Wcnt);
  e1_kernel<<<64, 256, 0, stream>>>(S, Gx, U);
  e2_kernel<<<64, 256, 0, stream>>>(U, Gx, Wcnt, cen, lr, out);
}

// Round 2
// 228.108 us; speedup vs baseline: 1.5612x; 1.5612x over previous
//
#include <hip/hip_runtime.h>
#include <cstdint>
#include <cstddef>

#define DIM    256
#define BATCH  4096
#define GRID_N 4096

typedef _Float16 f16x8 __attribute__((ext_vector_type(8)));
typedef _Float16 f16x4 __attribute__((ext_vector_type(4)));
typedef float    f32x4 __attribute__((ext_vector_type(4)));

// ---- ws float-slot offsets (regions overlap across pipeline phases) ----
#define OFF_APK  0u        // 4096x512 halfs [hi|lo] = 1048576 float slots (pack..gemm)
#define OFF_S    0u        // 4096x256 f32 (memset after gemm; finalize..e1)
#define OFF_BPK  1048576u  // 4096x512 halfs (pack..gemm)
#define OFF_CNT  1048576u  // 4096 f32 (memset after gemm)
#define OFF_U    1052672u  // 64x64x256 f32 (e1..e2) ..2101248
#define OFF_GX   2101248u
#define OFF_WCNT 2105344u
#define OFF_XN   2109440u
#define OFF_CN   2113536u
#define OFF_MD   2117632u
#define OFF_PV   2121728u
#define OFF_PI   2252800u  // ..2383872 (9.54 MB total)

// ---- out float offsets ----
#define OUT_BMU  1048576u
#define OUT_MD   1056768u

__device__ __forceinline__ void load_lds16(const void* g, void* l) {
  __builtin_amdgcn_global_load_lds(
      (const __attribute__((address_space(1))) unsigned int*)g,
      (__attribute__((address_space(3))) unsigned int*)l, 16, 0, 0);
}

// ---------------- pack f16 hi/lo + norms + Gx (block 0) ----------------
__global__ __launch_bounds__(256) void packnorm_kernel(
    const float* __restrict__ x, const float* __restrict__ cen,
    const float* __restrict__ lr,
    _Float16* __restrict__ Apk, _Float16* __restrict__ Bpk,
    float* __restrict__ xn, float* __restrict__ cn, float* __restrict__ Gx) {
  int row  = blockIdx.x * 4 + (threadIdx.x >> 6);
  int lane = threadIdx.x & 63;
  bool isx = row < BATCH;
  const float* src = isx ? (x + (size_t)row * DIM)
                         : (cen + (size_t)(row - BATCH) * DIM);
  float4 v = *(const float4*)(src + lane * 4);

  _Float16 h0 = (_Float16)v.x, h1 = (_Float16)v.y,
           h2 = (_Float16)v.z, h3 = (_Float16)v.w;
  _Float16 l0 = (_Float16)(v.x - (float)h0), l1 = (_Float16)(v.y - (float)h1),
           l2 = (_Float16)(v.z - (float)h2), l3 = (_Float16)(v.w - (float)h3);

  _Float16* dst = (isx ? Apk : Bpk) + (size_t)(isx ? row : row - BATCH) * 512;
  *(f16x4*)(dst + lane * 4)       = (f16x4){h0, h1, h2, h3};
  *(f16x4*)(dst + 256 + lane * 4) = (f16x4){l0, l1, l2, l3};

  float s = v.x * v.x + v.y * v.y + v.z * v.z + v.w * v.w;
#pragma unroll
  for (int off = 32; off >= 1; off >>= 1) s += __shfl_xor(s, off);
  if (lane == 0) {
    if (isx) xn[row] = s;
    else     cn[row - BATCH] = s;
  }

  if (blockIdx.x == 0) {
    float sg  = 32.f * lr[0];
    float inv = 1.f / (2.f * sg * sg + 1e-5f);
#pragma unroll
    for (int i = 0; i < 16; ++i) {
      int g = i * 256 + threadIdx.x;
      float d = (float)((g >> 6) - (g & 63));
      Gx[g] = expf(-d * d * inv);
    }
  }
}

// ------- MFMA f16-split GEMM (virtual K=768) + fused per-row argmin -------
__global__ __launch_bounds__(256) void gemm_argmin_kernel(
    const _Float16* __restrict__ Apk, const _Float16* __restrict__ Bpk,
    const float* __restrict__ cnorm, float* __restrict__ pv, int* __restrict__ pi) {
  __shared__ __align__(16) _Float16 As[4096];   // [128][32]
  __shared__ __align__(16) _Float16 Bs[4096];   // [128][32]
  const int tid  = threadIdx.x;
  const int lane = tid & 63, w = tid >> 6;
  const int wr = w >> 1, wc = w & 1;
  const int row0 = blockIdx.y * 128, col0 = blockIdx.x * 128;
  const int t15 = lane & 15, q = lane >> 4;
  const int rA = lane >> 2;            // row within 16-row segment
  const int cA = (lane & 3) * 8;       // half-offset (16B chunk) within row

  f32x4 acc[4][4];
#pragma unroll
  for (int m = 0; m < 4; ++m)
#pragma unroll
    for (int n = 0; n < 4; ++n) acc[m][n] = (f32x4){0.f, 0.f, 0.f, 0.f};

  for (int step = 0; step < 24; ++step) {
    const int term = step >> 3;          // 0: hh, 1: hl, 2: lh
    const int k256 = (step & 7) << 5;
    const int acb  = (term == 2 ? 256 : 0) + k256;
    const int bcb  = (term == 1 ? 256 : 0) + k256;
#pragma unroll
    for (int s = 0; s < 2; ++s) {
      const int seg = 2 * w + s;
      const int r   = seg * 16 + rA;
      load_lds16(Apk + (size_t)(row0 + r) * 512 + acb + cA, &As[seg * 512]);
      load_lds16(Bpk + (size_t)(col0 + r) * 512 + bcb + cA, &Bs[seg * 512]);
    }
    __syncthreads();                     // drains vmcnt for global_load_lds
    f16x8 af[4], bf[4];
#pragma unroll
    for (int m = 0; m < 4; ++m)
      af[m] = *(const f16x8*)&As[(wr * 64 + m * 16 + t15) * 32 + q * 8];
#pragma unroll
    for (int n = 0; n < 4; ++n)
      bf[n] = *(const f16x8*)&Bs[(wc * 64 + n * 16 + t15) * 32 + q * 8];
#pragma unroll
    for (int m = 0; m < 4; ++m)
#pragma unroll
      for (int n = 0; n < 4; ++n)
        acc[m][n] = __builtin_amdgcn_mfma_f32_16x16x32_f16(af[m], bf[n], acc[m][n], 0, 0, 0);
    __syncthreads();
  }

  // epilogue: v = cnorm[c] - 2*dot; per-row first-min over this 128-col block
  float cnv[4];
#pragma unroll
  for (int n = 0; n < 4; ++n) cnv[n] = cnorm[col0 + wc * 64 + n * 16 + t15];

  float* cv = (float*)As;   // [128][2]
  int*   ci = (int*)Bs;     // [128][2]
#pragma unroll
  for (int m = 0; m < 4; ++m) {
#pragma unroll
    for (int reg = 0; reg < 4; ++reg) {
      float bv = 1e30f; int bi = 0x7fffffff;
#pragma unroll
      for (int n = 0; n < 4; ++n) {     // cols ascend with n -> first-min
        float v = cnv[n] - 2.f * acc[m][n][reg];
        if (v < bv) { bv = v; bi = col0 + wc * 64 + n * 16 + t15; }
      }
#pragma unroll
      for (int off = 1; off < 16; off <<= 1) {   // reduce across 16 lanes of row
        float ov = __shfl_xor(bv, off);
        int   oi = __shfl_xor(bi, off);
        if (ov < bv || (ov == bv && oi < bi)) { bv = ov; bi = oi; }
      }
      if (t15 == 0) {
        int r = wr * 64 + m * 16 + q * 4 + reg;
        cv[r * 2 + wc] = bv;
        ci[r * 2 + wc] = bi;
      }
    }
  }
  __syncthreads();
  if (tid < 128) {
    float v0 = cv[tid * 2];     int i0 = ci[tid * 2];
    float v1 = cv[tid * 2 + 1]; int i1 = ci[tid * 2 + 1];
    if (v1 < v0 || (v1 == v0 && i1 < i0)) { v0 = v1; i0 = i1; }
    pv[(size_t)(row0 + tid) * 32 + blockIdx.x] = v0;
    pi[(size_t)(row0 + tid) * 32 + blockIdx.x] = i0;
  }
}

// ---------------- finalize: BMU per row, bmu_loc out, scatter S/cnt ----------------
__global__ __launch_bounds__(256) void finalize_kernel(
    const float* __restrict__ pv, const int* __restrict__ pi,
    const float* __restrict__ xn, const float* __restrict__ x,
    float* __restrict__ S, float* __restrict__ cnt,
    float* __restrict__ md, float* __restrict__ out) {
  const int b = blockIdx.x;
  const int tid = threadIdx.x;
  __shared__ int sbmu;
  if (tid < 64) {
    float v = 1e30f; int idx = 0x7fffffff;
    if (tid < 32) { v = pv[(size_t)b * 32 + tid]; idx = pi[(size_t)b * 32 + tid]; }
#pragma unroll
    for (int off = 16; off >= 1; off >>= 1) {
      float ov = __shfl_xor(v, off);
      int oi = __shfl_xor(idx, off);
      if (ov < v || (ov == v && oi < idx)) { v = ov; idx = oi; }
    }
    if (tid == 0) {
      sbmu = idx;
      float d2 = xn[b] + v;
      md[b] = sqrtf(fmaxf(d2, 0.f));
      out[OUT_BMU + (size_t)b * 2 + 0] = (float)(idx >> 6);
      out[OUT_BMU + (size_t)b * 2 + 1] = (float)(idx & 63);
      atomicAdd(cnt + idx, 1.f);
    }
  }
  __syncthreads();
  int bmu = sbmu;
  atomicAdd(S + (size_t)bmu * DIM + tid, x[(size_t)b * DIM + tid]);
}

// ------- Wcnt = (Gx (x) Gx) @ cnt ; block 0 also reduces mean(mindist) -------
__global__ __launch_bounds__(256) void wcnt_kernel(const float* __restrict__ cnt,
                                                   const float* __restrict__ Gx,
                                                   const float* __restrict__ md,
                                                   float* __restrict__ Wcnt,
                                                   float* __restrict__ out) {
  __shared__ float cs[4096], gs[4096], inner[4096];
  const int t = threadIdx.x;
  for (int i = 0; i < 16; i++) { cs[i * 256 + t] = cnt[i * 256 + t]; gs[i * 256 + t] = Gx[i * 256 + t]; }
  __syncthreads();
  for (int i = 0; i < 16; i++) {
    int idx = i * 256 + t; int ki = idx >> 6, gj = idx & 63;
    float a = 0.f;
    for (int kj = 0; kj < 64; kj++) a += gs[kj * 64 + gj] * cs[ki * 64 + kj];
    inner[idx] = a;
  }
  __syncthreads();
  const int g = blockIdx.x * 256 + t, gi = g >> 6, gj = g & 63;
  float a = 0.f;
  for (int ki = 0; ki < 64; ki++) a += gs[gi * 64 + ki] * inner[ki * 64 + gj];
  Wcnt[g] = a;

  if (blockIdx.x == 0) {
    float s = 0.f;
#pragma unroll
    for (int i = 0; i < 16; i++) s += md[i * 256 + t];
#pragma unroll
    for (int off = 32; off >= 1; off >>= 1) s += __shfl_xor(s, off);
    __shared__ float wsum[4];
    if ((t & 63) == 0) wsum[t >> 6] = s;
    __syncthreads();
    if (t == 0) out[OUT_MD] = (wsum[0] + wsum[1] + wsum[2] + wsum[3]) * (1.f / (float)BATCH);
  }
}

// ---------------- U[gi][kj][d] = sum_ki Gx[gi][ki] * S[ki][kj][d] ----------------
__global__ __launch_bounds__(256) void e1_kernel(const float* __restrict__ S,
                                                 const float* __restrict__ Gx,
                                                 float* __restrict__ U) {
  __shared__ float Ss[64 * 256];
  const int t = threadIdx.x;
  const int kj = blockIdx.x;
  for (int ki = 0; ki < 64; ki++)
    Ss[ki * 256 + t] = S[((size_t)ki * 64 + kj) * 256 + t];
  __syncthreads();
  for (int g0 = 0; g0 < 64; g0 += 8) {
    float a[8] = {0, 0, 0, 0, 0, 0, 0, 0};
    for (int ki = 0; ki < 64; ki++) {
      float s = Ss[ki * 256 + t];
#pragma unroll
      for (int qq = 0; qq < 8; qq++) a[qq] += Gx[(g0 + qq) * 64 + ki] * s;
    }
#pragma unroll
    for (int qq = 0; qq < 8; qq++)
      U[((size_t)(g0 + qq) * 64 + kj) * 256 + t] = a[qq];
  }
}

// -------- V + fused final centroid write --------
__global__ __launch_bounds__(256) void e2_kernel(const float* __restrict__ U,
                                                 const float* __restrict__ Gx,
                                                 const float* __restrict__ Wcnt,
                                                 const float* __restrict__ cen,
                                                 const float* __restrict__ lr,
                                                 float* __restrict__ out) {
  __shared__ float Us[64 * 256];
  const int t = threadIdx.x;
  const int gi = blockIdx.x;
  for (int kj = 0; kj < 64; kj++)
    Us[kj * 256 + t] = U[((size_t)gi * 64 + kj) * 256 + t];
  __syncthreads();
  const float coef = 0.5f * lr[0] / (float)BATCH;
  for (int g0 = 0; g0 < 64; g0 += 8) {
    float a[8] = {0, 0, 0, 0, 0, 0, 0, 0};
    for (int kj = 0; kj < 64; kj++) {
      float s = Us[kj * 256 + t];
#pragma unroll
      for (int qq = 0; qq < 8; qq++) a[qq] += Gx[(g0 + qq) * 64 + kj] * s;
    }
#pragma unroll
    for (int qq = 0; qq < 8; qq++) {
      int g = gi * 64 + g0 + qq;
      float c = cen[(size_t)g * 256 + t];
      out[(size_t)g * 256 + t] = c + coef * (a[qq] - Wcnt[g] * c);
    }
  }
}

extern "C" void kernel_launch(void* const* d_in, const int* in_sizes, int n_in,
                              void* d_out, int out_size, void* d_ws, size_t ws_size,
                              hipStream_t stream) {
  const float* x   = (const float*)d_in[0];
  const float* cen = (const float*)d_in[1];
  const float* lr  = (const float*)d_in[4];
  float* out = (float*)d_out;
  float* ws  = (float*)d_ws;

  _Float16* Apk = (_Float16*)(ws + OFF_APK);
  _Float16* Bpk = (_Float16*)(ws + OFF_BPK);
  float* S    = ws + OFF_S;
  float* cnt  = ws + OFF_CNT;
  float* U    = ws + OFF_U;
  float* Gx   = ws + OFF_GX;
  float* Wcnt = ws + OFF_WCNT;
  float* xn   = ws + OFF_XN;
  float* cnw  = ws + OFF_CN;
  float* md   = ws + OFF_MD;
  float* pv   = ws + OFF_PV;
  int*   pi   = (int*)(ws + OFF_PI);

  packnorm_kernel<<<2048, 256, 0, stream>>>(x, cen, lr, Apk, Bpk, xn, cnw, Gx);
  gemm_argmin_kernel<<<dim3(32, 32), 256, 0, stream>>>(Apk, Bpk, cnw, pv, pi);
  hipMemsetAsync(S, 0, (size_t)(1048576 + 4096) * sizeof(float), stream);  // S+cnt (over Apk/Bpk head)
  finalize_kernel<<<4096, 256, 0, stream>>>(pv, pi, xn, x, S, cnt, md, out);
  wcnt_kernel<<<16, 256, 0, stream>>>(cnt, Gx, md, Wcnt, out);
  e1_kernel<<<64, 256, 0, stream>>>(S, Gx, U);
  e2_kernel<<<64, 256, 0, stream>>>(U, Gx, Wcnt, cen, lr, out);
}

// Round 4
// 187.297 us; speedup vs baseline: 1.9014x; 1.2179x over previous
//
#include <hip/hip_runtime.h>
#include <cstdint>
#include <cstddef>

#define DIM    256
#define BATCH  4096
#define GRID_N 4096
#define STEPS  12

typedef _Float16 f16x8 __attribute__((ext_vector_type(8)));
typedef _Float16 f16x4 __attribute__((ext_vector_type(4)));
typedef float    f32x4 __attribute__((ext_vector_type(4)));

// ---- ws float-slot offsets (regions overlap across pipeline phases) ----
#define OFF_APK  0u        // 4096x512 halfs [hi|lo] (pack..gemm)
#define OFF_S    0u        // 4096x256 f32 (memset after gemm)
#define OFF_BPK  1048576u  // 4096x512 halfs (pack..gemm)
#define OFF_CNT  1048576u  // 4096 f32
#define OFF_U    1052672u  // 64x64x256 f32 (e1..e2)
#define OFF_GX   2101248u
#define OFF_WCNT 2105344u
#define OFF_XN   2109440u
#define OFF_CN   2113536u
#define OFF_MD   2117632u
#define OFF_PV   2121728u
#define OFF_PI   2252800u  // ..2383872

// ---- out float offsets ----
#define OUT_BMU  1048576u
#define OUT_MD   1056768u

__device__ __forceinline__ void load_lds16(const void* g, void* l) {
  __builtin_amdgcn_global_load_lds(
      (const __attribute__((address_space(1))) unsigned int*)g,
      (__attribute__((address_space(3))) unsigned int*)l, 16, 0, 0);
}

// ---------------- pack f16 hi/lo + norms + Gx (block 0) ----------------
__global__ __launch_bounds__(256) void packnorm_kernel(
    const float* __restrict__ x, const float* __restrict__ cen,
    const float* __restrict__ lr,
    _Float16* __restrict__ Apk, _Float16* __restrict__ Bpk,
    float* __restrict__ xn, float* __restrict__ cn, float* __restrict__ Gx) {
  int row  = blockIdx.x * 4 + (threadIdx.x >> 6);
  int lane = threadIdx.x & 63;
  bool isx = row < BATCH;
  const float* src = isx ? (x + (size_t)row * DIM)
                         : (cen + (size_t)(row - BATCH) * DIM);
  float4 v = *(const float4*)(src + lane * 4);

  _Float16 h0 = (_Float16)v.x, h1 = (_Float16)v.y,
           h2 = (_Float16)v.z, h3 = (_Float16)v.w;
  _Float16 l0 = (_Float16)(v.x - (float)h0), l1 = (_Float16)(v.y - (float)h1),
           l2 = (_Float16)(v.z - (float)h2), l3 = (_Float16)(v.w - (float)h3);

  _Float16* dst = (isx ? Apk : Bpk) + (size_t)(isx ? row : row - BATCH) * 512;
  *(f16x4*)(dst + lane * 4)       = (f16x4){h0, h1, h2, h3};
  *(f16x4*)(dst + 256 + lane * 4) = (f16x4){l0, l1, l2, l3};

  float s = v.x * v.x + v.y * v.y + v.z * v.z + v.w * v.w;
#pragma unroll
  for (int off = 32; off >= 1; off >>= 1) s += __shfl_xor(s, off);
  if (lane == 0) {
    if (isx) xn[row] = s;
    else     cn[row - BATCH] = s;
  }

  if (blockIdx.x == 0) {
    float sg  = 32.f * lr[0];
    float inv = 1.f / (2.f * sg * sg + 1e-5f);
#pragma unroll
    for (int i = 0; i < 16; ++i) {
      int g = i * 256 + threadIdx.x;
      float d = (float)((g >> 6) - (g & 63));
      Gx[g] = expf(-d * d * inv);
    }
  }
}

// ------- MFMA f16-split GEMM, BK=64, 2-phase dbuf, XOR-swizzled LDS -------
__global__ __launch_bounds__(256) void gemm_argmin_kernel(
    const _Float16* __restrict__ Apk, const _Float16* __restrict__ Bpk,
    const float* __restrict__ cnorm, float* __restrict__ pv, int* __restrict__ pi) {
  __shared__ __align__(16) _Float16 lds[2][2][8192];   // [buf][A/B][128r x 64k]
  const int tid  = threadIdx.x;
  const int lane = tid & 63, w = tid >> 6;
  const int wr = w >> 1, wc = w & 1;
  const int row0 = blockIdx.y * 128, col0 = blockIdx.x * 128;
  const int t15 = lane & 15, q = lane >> 4;
  const int sw  = t15 & 7;                       // read-side row-swizzle key
  const int srow   = w * 32 + (lane >> 3);       // staging row (+ i*8)
  const int schunk = (lane & 7) ^ ((lane >> 3) & 7);  // pre-swizzled source chunk

  f32x4 acc[4][4];
#pragma unroll
  for (int m = 0; m < 4; ++m)
#pragma unroll
    for (int n = 0; n < 4; ++n) acc[m][n] = (f32x4){0.f, 0.f, 0.f, 0.f};

  auto STAGE = [&](int b, int step) {
    const int seg = step >> 2, k = (step & 3) << 6;
    const int aoff = ((seg == 2) ? 256 : 0) + k;   // halfs: term 2 uses A-lo
    const int boff = ((seg == 1) ? 256 : 0) + k;   // halfs: term 1 uses B-lo
    const _Float16* Ab = Apk + (size_t)(row0 + srow) * 512 + aoff + schunk * 8;
    const _Float16* Bb = Bpk + (size_t)(col0 + srow) * 512 + boff + schunk * 8;
    _Float16* Al = &lds[b][0][w * 2048];
    _Float16* Bl = &lds[b][1][w * 2048];
#pragma unroll
    for (int i = 0; i < 4; ++i) {
      load_lds16(Ab + (size_t)i * 8 * 512, Al + i * 512);
      load_lds16(Bb + (size_t)i * 8 * 512, Bl + i * 512);
    }
  };

  STAGE(0, 0);
  for (int t = 0; t < STEPS; ++t) {
    const int b = t & 1;
    __syncthreads();                    // drains vmcnt(0): tile t staged; lgkm too
    if (t + 1 < STEPS) STAGE(b ^ 1, t + 1);
#pragma unroll
    for (int kk = 0; kk < 2; ++kk) {
      f16x8 af[4], bf[4];
#pragma unroll
      for (int m = 0; m < 4; ++m) {
        int r = wr * 64 + m * 16 + t15;
        af[m] = *(const f16x8*)&lds[b][0][r * 64 + (((kk * 4 + q) ^ sw) * 8)];
      }
#pragma unroll
      for (int n = 0; n < 4; ++n) {
        int r = wc * 64 + n * 16 + t15;
        bf[n] = *(const f16x8*)&lds[b][1][r * 64 + (((kk * 4 + q) ^ sw) * 8)];
      }
#pragma unroll
      for (int m = 0; m < 4; ++m)
#pragma unroll
        for (int n = 0; n < 4; ++n)
          acc[m][n] = __builtin_amdgcn_mfma_f32_16x16x32_f16(af[m], bf[n], acc[m][n], 0, 0, 0);
    }
  }
  __syncthreads();                      // all ds_reads done before LDS reuse

  // epilogue: v = cnorm[c] - 2*dot; per-row first-min over this 128-col block
  float cnv[4];
#pragma unroll
  for (int n = 0; n < 4; ++n) cnv[n] = cnorm[col0 + wc * 64 + n * 16 + t15];

  float* cv = (float*)&lds[0][0][0];   // [128][2]
  int*   ci = (int*)&lds[0][1][0];     // [128][2]
#pragma unroll
  for (int m = 0; m < 4; ++m) {
#pragma unroll
    for (int reg = 0; reg < 4; ++reg) {
      float bv = 1e30f; int bi = 0x7fffffff;
#pragma unroll
      for (int n = 0; n < 4; ++n) {     // cols ascend with n -> first-min
        float v = cnv[n] - 2.f * acc[m][n][reg];
        if (v < bv) { bv = v; bi = col0 + wc * 64 + n * 16 + t15; }
      }
#pragma unroll
      for (int off = 1; off < 16; off <<= 1) {
        float ov = __shfl_xor(bv, off);
        int   oi = __shfl_xor(bi, off);
        if (ov < bv || (ov == bv && oi < bi)) { bv = ov; bi = oi; }
      }
      if (t15 == 0) {
        int r = wr * 64 + m * 16 + q * 4 + reg;
        cv[r * 2 + wc] = bv;
        ci[r * 2 + wc] = bi;
      }
    }
  }
  __syncthreads();
  if (tid < 128) {
    float v0 = cv[tid * 2];     int i0 = ci[tid * 2];
    float v1 = cv[tid * 2 + 1]; int i1 = ci[tid * 2 + 1];
    if (v1 < v0 || (v1 == v0 && i1 < i0)) { v0 = v1; i0 = i1; }
    pv[(size_t)(row0 + tid) * 32 + blockIdx.x] = v0;
    pi[(size_t)(row0 + tid) * 32 + blockIdx.x] = i0;
  }
}

// ------- finalize: 4 rows/block, wavewide reduce, no LDS, scatter S/cnt -------
__global__ __launch_bounds__(256) void finalize_kernel(
    const float* __restrict__ pv, const int* __restrict__ pi,
    const float* __restrict__ xn, const float* __restrict__ x,
    float* __restrict__ S, float* __restrict__ cnt,
    float* __restrict__ md, float* __restrict__ out) {
  const int w = threadIdx.x >> 6, l = threadIdx.x & 63;
  const int b = blockIdx.x * 4 + w;
  float v = pv[(size_t)b * 32 + (l & 31)];     // both 32-halves load same data
  int idx  = pi[(size_t)b * 32 + (l & 31)];
#pragma unroll
  for (int off = 16; off >= 1; off >>= 1) {
    float ov = __shfl_xor(v, off);
    int   oi = __shfl_xor(idx, off);
    if (ov < v || (ov == v && oi < idx)) { v = ov; idx = oi; }
  }
  if (l == 0) {
    md[b] = sqrtf(fmaxf(xn[b] + v, 0.f));
    out[OUT_BMU + (size_t)b * 2 + 0] = (float)(idx >> 6);
    out[OUT_BMU + (size_t)b * 2 + 1] = (float)(idx & 63);
    atomicAdd(cnt + idx, 1.f);
  }
#pragma unroll
  for (int c = 0; c < 4; ++c)
    atomicAdd(S + (size_t)idx * DIM + c * 64 + l, x[(size_t)b * DIM + c * 64 + l]);
}

// ------- Wcnt = (Gx (x) Gx) @ cnt ; block 0 also reduces mean(mindist) -------
__global__ __launch_bounds__(256) void wcnt_kernel(const float* __restrict__ cnt,
                                                   const float* __restrict__ Gx,
                                                   const float* __restrict__ md,
                                                   float* __restrict__ Wcnt,
                                                   float* __restrict__ out) {
  __shared__ float cs[4096], gs[4096], inner[4096];
  const int t = threadIdx.x;
  for (int i = 0; i < 16; i++) { cs[i * 256 + t] = cnt[i * 256 + t]; gs[i * 256 + t] = Gx[i * 256 + t]; }
  __syncthreads();
  for (int i = 0; i < 16; i++) {
    int idx = i * 256 + t; int ki = idx >> 6, gj = idx & 63;
    float a = 0.f;
    for (int kj = 0; kj < 64; kj++) a += gs[kj * 64 + gj] * cs[ki * 64 + kj];
    inner[idx] = a;
  }
  __syncthreads();
  const int g = blockIdx.x * 256 + t, gi = g >> 6, gj = g & 63;
  float a = 0.f;
  for (int ki = 0; ki < 64; ki++) a += gs[gi * 64 + ki] * inner[ki * 64 + gj];
  Wcnt[g] = a;

  if (blockIdx.x == 0) {
    float s = 0.f;
#pragma unroll
    for (int i = 0; i < 16; i++) s += md[i * 256 + t];
#pragma unroll
    for (int off = 32; off >= 1; off >>= 1) s += __shfl_xor(s, off);
    __shared__ float wsum[4];
    if ((t & 63) == 0) wsum[t >> 6] = s;
    __syncthreads();
    if (t == 0) out[OUT_MD] = (wsum[0] + wsum[1] + wsum[2] + wsum[3]) * (1.f / (float)BATCH);
  }
}

// --- U[gi][kj][d] = sum_ki Gx[gi][ki]*S[ki][kj][d] ; grid (kj,dquad)=256 ---
__global__ __launch_bounds__(256) void e1_kernel(const float* __restrict__ S,
                                                 const float* __restrict__ Gx,
                                                 float* __restrict__ U) {
  __shared__ float Ss[4096];            // [64 ki][64 dd]
  const int t = threadIdx.x, dd = t & 63, gq = t >> 6;
  const int kj = blockIdx.x >> 2, dq = blockIdx.x & 3;
#pragma unroll 4
  for (int i = 0; i < 16; ++i) {
    int ki = i * 4 + gq;
    Ss[ki * 64 + dd] = S[((size_t)ki * 64 + kj) * 256 + dq * 64 + dd];
  }
  __syncthreads();
  float a[16];
#pragma unroll
  for (int gg = 0; gg < 16; ++gg) a[gg] = 0.f;
  for (int ki = 0; ki < 64; ++ki) {
    float s = Ss[ki * 64 + dd];
#pragma unroll
    for (int gg = 0; gg < 16; ++gg)
      a[gg] += Gx[ki * 64 + gq * 16 + gg] * s;   // Gx symmetric -> contiguous s_loads
  }
#pragma unroll
  for (int gg = 0; gg < 16; ++gg)
    U[((size_t)(gq * 16 + gg) * 64 + kj) * 256 + dq * 64 + dd] = a[gg];
}

// --- V + fused centroid write ; grid (gi,dquad)=256 ---
__global__ __launch_bounds__(256) void e2_kernel(const float* __restrict__ U,
                                                 const float* __restrict__ Gx,
                                                 const float* __restrict__ Wcnt,
                                                 const float* __restrict__ cen,
                                                 const float* __restrict__ lr,
                                                 float* __restrict__ out) {
  __shared__ float Us[4096];            // [64 kj][64 dd]
  const int t = threadIdx.x, dd = t & 63, gq = t >> 6;
  const int gi = blockIdx.x >> 2, dq = blockIdx.x & 3;
#pragma unroll 4
  for (int i = 0; i < 16; ++i) {
    int kj = i * 4 + gq;
    Us[kj * 64 + dd] = U[((size_t)gi * 64 + kj) * 256 + dq * 64 + dd];
  }
  __syncthreads();
  float a[16];
#pragma unroll
  for (int gg = 0; gg < 16; ++gg) a[gg] = 0.f;
  for (int kj = 0; kj < 64; ++kj) {
    float s = Us[kj * 64 + dd];
#pragma unroll
    for (int gg = 0; gg < 16; ++gg)
      a[gg] += Gx[kj * 64 + gq * 16 + gg] * s;
  }
  const float coef = 0.5f * lr[0] / (float)BATCH;
#pragma unroll
  for (int gg = 0; gg < 16; ++gg) {
    int g = gi * 64 + gq * 16 + gg;
    float c = cen[(size_t)g * 256 + dq * 64 + dd];
    out[(size_t)g * 256 + dq * 64 + dd] = c + coef * (a[gg] - Wcnt[g] * c);
  }
}

extern "C" void kernel_launch(void* const* d_in, const int* in_sizes, int n_in,
                              void* d_out, int out_size, void* d_ws, size_t ws_size,
                              hipStream_t stream) {
  const float* x   = (const float*)d_in[0];
  const float* cen = (const float*)d_in[1];
  const float* lr  = (const float*)d_in[4];
  float* out = (float*)d_out;
  float* ws  = (float*)d_ws;

  _Float16* Apk = (_Float16*)(ws + OFF_APK);
  _Float16* Bpk = (_Float16*)(ws + OFF_BPK);
  float* S    = ws + OFF_S;
  float* cnt  = ws + OFF_CNT;
  float* U    = ws + OFF_U;
  float* Gx   = ws + OFF_GX;
  float* Wcnt = ws + OFF_WCNT;
  float* xn   = ws + OFF_XN;
  float* cnw  = ws + OFF_CN;
  float* md   = ws + OFF_MD;
  float* pv   = ws + OFF_PV;
  int*   pi   = (int*)(ws + OFF_PI);

  packnorm_kernel<<<2048, 256, 0, stream>>>(x, cen, lr, Apk, Bpk, xn, cnw, Gx);
  gemm_argmin_kernel<<<dim3(32, 32), 256, 0, stream>>>(Apk, Bpk, cnw, pv, pi);
  hipMemsetAsync(S, 0, (size_t)(1048576 + 4096) * sizeof(float), stream);  // S+cnt
  finalize_kernel<<<1024, 256, 0, stream>>>(pv, pi, xn, x, S, cnt, md, out);
  wcnt_kernel<<<16, 256, 0, stream>>>(cnt, Gx, md, Wcnt, out);
  e1_kernel<<<256, 256, 0, stream>>>(S, Gx, U);
  e2_kernel<<<256, 256, 0, stream>>>(U, Gx, Wcnt, cen, lr, out);
}